// Round 1
// baseline (1210.056 us; speedup 1.0000x reference)
//
#include <hip/hip_runtime.h>
#include <math.h>

#define NN 200000      // nodes
#define NE 6400000     // edges
#define FIN 100        // input feature dim
#define MR 10000       // sampled rows (NN/20)
#define SCAN_NB 196    // ceil(NN/1024)

// ---------- float <-> monotonic-uint encoding for atomic min/max ----------
static __device__ __forceinline__ unsigned enc_f(float f){
  unsigned u = __float_as_uint(f);
  return (u & 0x80000000u) ? ~u : (u | 0x80000000u);
}
static __device__ __forceinline__ float dec_f(unsigned u){
  return (u & 0x80000000u) ? __uint_as_float(u ^ 0x80000000u) : __uint_as_float(~u);
}

// ---------- init: deg=1 (self loop), offs[NN]=NE, minmax identity ----------
__global__ void k_init(int* deg, int* offs, unsigned* mm){
  int i = blockIdx.x*blockDim.x + threadIdx.x;
  if(i < NN) deg[i] = 1;
  if(i == 0){ offs[NN] = NE; mm[0] = 0xFFFFFFFFu; mm[1] = 0u; }
}

// ---------- in-degree histogram ----------
__global__ void k_deg(const int* __restrict__ dst, int* __restrict__ deg){
  int e = blockIdx.x*blockDim.x + threadIdx.x;
  if(e < NE) atomicAdd(&deg[dst[e]], 1);
}

__global__ void k_dinv(const int* __restrict__ deg, float* __restrict__ dinv){
  int i = blockIdx.x*blockDim.x + threadIdx.x;
  if(i < NN) dinv[i] = rsqrtf((float)deg[i]);
}

// ---------- 3-kernel exclusive scan of edge counts (deg-1), chunk=1024 ----------
__global__ void k_scan_part(const int* __restrict__ deg, int* __restrict__ part){
  __shared__ int sh[256];
  int b = blockIdx.x, t = threadIdx.x;
  int base = b*1024 + t*4;
  int s = 0;
  #pragma unroll
  for(int j=0;j<4;j++){ int i = base+j; if(i < NN) s += deg[i]-1; }
  sh[t] = s; __syncthreads();
  for(int o=128;o>0;o>>=1){ if(t<o) sh[t] += sh[t+o]; __syncthreads(); }
  if(t==0) part[b] = sh[0];
}

__global__ void k_scan_top(int* part, int nb){
  __shared__ int sh[256];
  int t = threadIdx.x;
  int v = (t<nb) ? part[t] : 0;
  sh[t] = v; __syncthreads();
  for(int o=1;o<256;o<<=1){
    int x = (t>=o) ? sh[t-o] : 0;
    __syncthreads();
    sh[t] += x;
    __syncthreads();
  }
  if(t<nb) part[t] = sh[t] - v;   // exclusive
}

__global__ void k_scan_fin(const int* __restrict__ deg, const int* __restrict__ part,
                           int* __restrict__ offs, int* __restrict__ cursor){
  __shared__ int sh[256];
  int b = blockIdx.x, t = threadIdx.x;
  int base = b*1024 + t*4;
  int c[4]; int s = 0;
  #pragma unroll
  for(int j=0;j<4;j++){ int i = base+j; c[j] = (i < NN) ? deg[i]-1 : 0; s += c[j]; }
  sh[t] = s; __syncthreads();
  for(int o=1;o<256;o<<=1){
    int x = (t>=o) ? sh[t-o] : 0;
    __syncthreads();
    sh[t] += x;
    __syncthreads();
  }
  int run = sh[t] - s + part[b];
  #pragma unroll
  for(int j=0;j<4;j++){
    int i = base+j;
    if(i < NN){ offs[i] = run; cursor[i] = run; }
    run += c[j];
  }
}

// ---------- CSR scatter (by dst) ----------
__global__ void k_scatter(const int* __restrict__ src, const int* __restrict__ dst,
                          int* __restrict__ cursor, int* __restrict__ csr){
  int e = blockIdx.x*blockDim.x + threadIdx.x;
  if(e < NE){
    int d = dst[e];
    int p = atomicAdd(&cursor[d], 1);
    csr[p] = src[e];
  }
}

// ---------- h1s[row][c] = dinv[row] * (x @ W1)[row][c], 16 cols ----------
__global__ __launch_bounds__(256) void k_xw1(const float* __restrict__ x,
                                             const float* __restrict__ W1,
                                             const float* __restrict__ dinv,
                                             float* __restrict__ h1s){
  int row = blockIdx.x*256 + threadIdx.x;
  if(row >= NN) return;
  const float4* xr = (const float4*)(x + (size_t)row*FIN);  // 400B rows, 16B aligned
  float acc[16];
  #pragma unroll
  for(int c=0;c<16;c++) acc[c] = 0.f;
  #pragma unroll 5
  for(int kk=0;kk<25;kk++){
    float4 xv = xr[kk];
    const float* w = W1 + kk*4*16;   // uniform addresses -> scalar loads
    #pragma unroll
    for(int c=0;c<16;c++){
      acc[c] += xv.x*w[c] + xv.y*w[16+c] + xv.z*w[32+c] + xv.w*w[48+c];
    }
  }
  float dv = dinv[row];
  float4* o = (float4*)(h1s + (size_t)row*16);
  o[0] = make_float4(acc[0]*dv,  acc[1]*dv,  acc[2]*dv,  acc[3]*dv);
  o[1] = make_float4(acc[4]*dv,  acc[5]*dv,  acc[6]*dv,  acc[7]*dv);
  o[2] = make_float4(acc[8]*dv,  acc[9]*dv,  acc[10]*dv, acc[11]*dv);
  o[3] = make_float4(acc[12]*dv, acc[13]*dv, acc[14]*dv, acc[15]*dv);
}

// ---------- layer-1 aggregation + bias + relu + @W2, fold dinv[d] into h2s ----------
// 16 lanes per node (lane = feature), 16 nodes per 256-thread block.
__global__ __launch_bounds__(256) void k_agg1(const int* __restrict__ offs,
                                              const int* __restrict__ csr,
                                              const float* __restrict__ dinv,
                                              const float* __restrict__ h1s,
                                              const float* __restrict__ b1,
                                              const float* __restrict__ W2,
                                              float* __restrict__ h2s){
  int g = threadIdx.x >> 4;
  int f = threadIdx.x & 15;
  int d = blockIdx.x*16 + g;
  if(d >= NN) return;
  int begin = offs[d], end = offs[d+1];
  float dvd = dinv[d];
  float acc = h1s[d*16 + f];            // self loop (dinv[d] folded in h1s)
  for(int base=begin; base<end; base+=16){
    int i = base + f;
    int sE = (i < end) ? csr[i] : 0;    // coalesced 64B per group
    int cnt = end - base; if(cnt > 16) cnt = 16;
    for(int j=0;j<cnt;j++){
      int sj = __shfl(sE, j, 16);
      acc += h1s[sj*16 + f];            // 16 lanes -> one 64B line
    }
  }
  float out1 = dvd*acc + b1[f];         // segment_sum(norm*h1) + b1
  float r = fmaxf(out1, 0.f);
  float p0 = r * W2[f*2+0];
  float p1 = r * W2[f*2+1];
  #pragma unroll
  for(int o=8;o>0;o>>=1){
    p0 += __shfl_xor(p0, o, 16);
    p1 += __shfl_xor(p1, o, 16);
  }
  if(f == 0){
    h2s[d*2+0] = dvd * p0;              // pre-fold dinv[d] for layer-2 gathers
    h2s[d*2+1] = dvd * p1;
  }
}

// ---------- layer-2 aggregation for sampled nodes only + log_softmax ----------
// one wave per sampled node
__global__ __launch_bounds__(256) void k_agg2(const int* __restrict__ offs,
                                              const int* __restrict__ csr,
                                              const float* __restrict__ dinv,
                                              const float* __restrict__ h2s,
                                              const float* __restrict__ b2,
                                              float* __restrict__ gout){
  int wid = threadIdx.x >> 6;
  int l   = threadIdx.x & 63;
  int idx = blockIdx.x*4 + wid;
  if(idx >= MR) return;
  int d = idx*20;
  int begin = offs[d], end = offs[d+1];
  float dvd = dinv[d];
  float a0 = 0.f, a1 = 0.f;
  for(int i=begin+l; i<end; i+=64){
    int s = csr[i];
    a0 += h2s[s*2+0];
    a1 += h2s[s*2+1];
  }
  if(l == 0){ a0 += h2s[d*2+0]; a1 += h2s[d*2+1]; }  // self loop
  #pragma unroll
  for(int o=32;o>0;o>>=1){
    a0 += __shfl_xor(a0, o, 64);
    a1 += __shfl_xor(a1, o, 64);
  }
  if(l == 0){
    float o0 = dvd*a0 + b2[0];
    float o1 = dvd*a1 + b2[1];
    float m = fmaxf(o0, o1);
    float lse = m + logf(expf(o0-m) + expf(o1-m));
    gout[idx*2+0] = o0 - lse;
    gout[idx*2+1] = o1 - lse;
  }
}

// ---------- global min/max over BP_input ([MR,5] = 3 inputs + gout) ----------
__global__ void k_minmax(const float* __restrict__ t1, const float* __restrict__ t2,
                         const float* __restrict__ t3, const float* __restrict__ g,
                         unsigned* mm){
  int tid = blockIdx.x*blockDim.x + threadIdx.x;
  float lo = 3.4e38f, hi = -3.4e38f;
  for(int i=tid; i<5*MR; i += blockDim.x*gridDim.x){
    float v;
    if(i < MR)        v = t1[i];
    else if(i < 2*MR) v = t2[i-MR];
    else if(i < 3*MR) v = t3[i-2*MR];
    else              v = g[i-3*MR];
    lo = fminf(lo, v); hi = fmaxf(hi, v);
  }
  #pragma unroll
  for(int o=32;o>0;o>>=1){
    lo = fminf(lo, __shfl_xor(lo, o, 64));
    hi = fmaxf(hi, __shfl_xor(hi, o, 64));
  }
  __shared__ float slo[4], shi[4];
  int w = threadIdx.x >> 6, l = threadIdx.x & 63;
  if(l == 0){ slo[w] = lo; shi[w] = hi; }
  __syncthreads();
  if(threadIdx.x == 0){
    for(int j=1;j<4;j++){ lo = fminf(lo, slo[j]); hi = fmaxf(hi, shi[j]); }
    atomicMin(&mm[0], enc_f(lo));
    atomicMax(&mm[1], enc_f(hi));
  }
}

// ---------- MLP head: normalize -> 5->80 relu -> 80->10 relu -> 10->1 sigmoid ----------
__global__ __launch_bounds__(256) void k_mlp(const float* __restrict__ t1, const float* __restrict__ t2,
                                             const float* __restrict__ t3, const float* __restrict__ g,
                                             const unsigned* __restrict__ mm,
                                             const float* __restrict__ W1, const float* __restrict__ b1,
                                             const float* __restrict__ W2, const float* __restrict__ b2,
                                             const float* __restrict__ W3, const float* __restrict__ b3,
                                             float* __restrict__ out){
  int i = blockIdx.x*256 + threadIdx.x;
  if(i >= MR) return;
  float mn = dec_f(mm[0]), mx = dec_f(mm[1]);
  float sc = 1.f/(mx - mn);
  float in[5];
  in[0] = (t1[i]   - mn)*sc;
  in[1] = (t2[i]   - mn)*sc;
  in[2] = (t3[i]   - mn)*sc;
  in[3] = (g[2*i]  - mn)*sc;
  in[4] = (g[2*i+1]- mn)*sc;
  float a[80];
  #pragma unroll
  for(int j=0;j<80;j++){
    float s = b1[j];
    #pragma unroll
    for(int k=0;k<5;k++) s += in[k]*W1[k*80+j];
    a[j] = fmaxf(s, 0.f);
  }
  float h[10];
  #pragma unroll
  for(int j=0;j<10;j++){
    float s = b2[j];
    #pragma unroll
    for(int k=0;k<80;k++) s += a[k]*W2[k*10+j];
    h[j] = fmaxf(s, 0.f);
  }
  float o = b3[0];
  #pragma unroll
  for(int k=0;k<10;k++) o += h[k]*W3[k];
  out[i] = 1.f/(1.f + expf(-o));
}

extern "C" void kernel_launch(void* const* d_in, const int* in_sizes, int n_in,
                              void* d_out, int out_size, void* d_ws, size_t ws_size,
                              hipStream_t stream) {
  (void)in_sizes; (void)n_in; (void)out_size; (void)ws_size;
  const int*   eidx    = (const int*)  d_in[0];   // [2, NE]
  const int*   src     = eidx;
  const int*   dst     = eidx + NE;
  const float* x       = (const float*)d_in[1];   // [NN, 100]
  const float* transE  = (const float*)d_in[4];
  const float* ComplEx = (const float*)d_in[5];
  const float* path    = (const float*)d_in[6];
  const float* ghW1    = (const float*)d_in[8];
  const float* ghb1    = (const float*)d_in[9];
  const float* ghW2    = (const float*)d_in[10];
  const float* ghb2    = (const float*)d_in[11];
  const float* mW1     = (const float*)d_in[16];
  const float* mb1     = (const float*)d_in[17];
  const float* mW2     = (const float*)d_in[18];
  const float* mb2     = (const float*)d_in[19];
  const float* mW3     = (const float*)d_in[20];
  const float* mb3     = (const float*)d_in[21];
  float* out = (float*)d_out;

  // workspace carve-up (~44 MB)
  char* w = (char*)d_ws;
  size_t off = 0;
  auto alloc = [&](size_t bytes)->void*{
    void* p = w + off;
    off += (bytes + 255) & ~(size_t)255;
    return p;
  };
  int*      deg    = (int*)     alloc((size_t)NN*4);
  int*      offs   = (int*)     alloc((size_t)(NN+1)*4);
  int*      cursor = (int*)     alloc((size_t)NN*4);
  int*      csr    = (int*)     alloc((size_t)NE*4);
  float*    dinv   = (float*)   alloc((size_t)NN*4);
  float*    h1s    = (float*)   alloc((size_t)NN*16*4);
  float*    h2s    = (float*)   alloc((size_t)NN*2*4);
  float*    gout   = (float*)   alloc((size_t)MR*2*4);
  unsigned* mm     = (unsigned*)alloc(256);
  int*      part   = (int*)     alloc(256*4);

  k_init     <<<(NN+255)/256, 256, 0, stream>>>(deg, offs, mm);
  k_deg      <<<(NE+255)/256, 256, 0, stream>>>(dst, deg);
  k_dinv     <<<(NN+255)/256, 256, 0, stream>>>(deg, dinv);
  k_scan_part<<<SCAN_NB, 256, 0, stream>>>(deg, part);
  k_scan_top <<<1, 256, 0, stream>>>(part, SCAN_NB);
  k_scan_fin <<<SCAN_NB, 256, 0, stream>>>(deg, part, offs, cursor);
  k_scatter  <<<(NE+255)/256, 256, 0, stream>>>(src, dst, cursor, csr);
  k_xw1      <<<(NN+255)/256, 256, 0, stream>>>(x, ghW1, dinv, h1s);
  k_agg1     <<<NN/16, 256, 0, stream>>>(offs, csr, dinv, h1s, ghb1, ghW2, h2s);
  k_agg2     <<<(MR+3)/4, 256, 0, stream>>>(offs, csr, dinv, h2s, ghb2, gout);
  k_minmax   <<<32, 256, 0, stream>>>(transE, ComplEx, path, gout, mm);
  k_mlp      <<<(MR+255)/256, 256, 0, stream>>>(transE, ComplEx, path, gout, mm,
                                                mW1, mb1, mW2, mb2, mW3, mb3, out);
}

// Round 2
// 1078.884 us; speedup vs baseline: 1.1216x; 1.1216x over previous
//
#include <hip/hip_runtime.h>
#include <math.h>

#define NN 200000      // nodes
#define NE 6400000     // edges
#define FIN 100        // input feature dim
#define MR 10000       // sampled rows (NN/20)
#define SCAN_NB 196    // ceil(NN/1024)
#define NPASS 8        // dst-range passes for deg/scatter (L2-resident windows)
#define PRANGE 25000   // NN / NPASS

// ---------- float <-> monotonic-uint encoding for atomic min/max ----------
static __device__ __forceinline__ unsigned enc_f(float f){
  unsigned u = __float_as_uint(f);
  return (u & 0x80000000u) ? ~u : (u | 0x80000000u);
}
static __device__ __forceinline__ float dec_f(unsigned u){
  return (u & 0x80000000u) ? __uint_as_float(u ^ 0x80000000u) : __uint_as_float(~u);
}

// ---------- init: deg=1 (self loop), offs[NN]=NE, minmax identity ----------
__global__ void k_init(int* deg, int* offs, unsigned* mm){
  int i = blockIdx.x*blockDim.x + threadIdx.x;
  if(i < NN) deg[i] = 1;
  if(i == 0){ offs[NN] = NE; mm[0] = 0xFFFFFFFFu; mm[1] = 0u; }
}

// ---------- in-degree histogram, dst-range partitioned ----------
// Only dsts in [lo,hi) are counted this pass -> atomics land in a 100KB
// L2-resident window instead of random over 800KB.
__global__ __launch_bounds__(256) void k_deg_pass(const int4* __restrict__ dst4,
                                                  int* __restrict__ deg,
                                                  int lo, int hi){
  int t = blockIdx.x*256 + threadIdx.x;    // t < NE/4
  int4 d = dst4[t];
  if(d.x>=lo && d.x<hi) atomicAdd(&deg[d.x], 1);
  if(d.y>=lo && d.y<hi) atomicAdd(&deg[d.y], 1);
  if(d.z>=lo && d.z<hi) atomicAdd(&deg[d.z], 1);
  if(d.w>=lo && d.w<hi) atomicAdd(&deg[d.w], 1);
}

__global__ void k_dinv(const int* __restrict__ deg, float* __restrict__ dinv){
  int i = blockIdx.x*blockDim.x + threadIdx.x;
  if(i < NN) dinv[i] = rsqrtf((float)deg[i]);
}

// ---------- 3-kernel exclusive scan of edge counts (deg-1), chunk=1024 ----------
__global__ void k_scan_part(const int* __restrict__ deg, int* __restrict__ part){
  __shared__ int sh[256];
  int b = blockIdx.x, t = threadIdx.x;
  int base = b*1024 + t*4;
  int s = 0;
  #pragma unroll
  for(int j=0;j<4;j++){ int i = base+j; if(i < NN) s += deg[i]-1; }
  sh[t] = s; __syncthreads();
  for(int o=128;o>0;o>>=1){ if(t<o) sh[t] += sh[t+o]; __syncthreads(); }
  if(t==0) part[b] = sh[0];
}

__global__ void k_scan_top(int* part, int nb){
  __shared__ int sh[256];
  int t = threadIdx.x;
  int v = (t<nb) ? part[t] : 0;
  sh[t] = v; __syncthreads();
  for(int o=1;o<256;o<<=1){
    int x = (t>=o) ? sh[t-o] : 0;
    __syncthreads();
    sh[t] += x;
    __syncthreads();
  }
  if(t<nb) part[t] = sh[t] - v;   // exclusive
}

__global__ void k_scan_fin(const int* __restrict__ deg, const int* __restrict__ part,
                           int* __restrict__ offs, int* __restrict__ cursor){
  __shared__ int sh[256];
  int b = blockIdx.x, t = threadIdx.x;
  int base = b*1024 + t*4;
  int c[4]; int s = 0;
  #pragma unroll
  for(int j=0;j<4;j++){ int i = base+j; c[j] = (i < NN) ? deg[i]-1 : 0; s += c[j]; }
  sh[t] = s; __syncthreads();
  for(int o=1;o<256;o<<=1){
    int x = (t>=o) ? sh[t-o] : 0;
    __syncthreads();
    sh[t] += x;
    __syncthreads();
  }
  int run = sh[t] - s + part[b];
  #pragma unroll
  for(int j=0;j<4;j++){
    int i = base+j;
    if(i < NN){ offs[i] = run; cursor[i] = run; }
    run += c[j];
  }
}

// ---------- CSR scatter (by dst), dst-range partitioned ----------
// Pass p only scatters edges whose dst is in [lo,hi): cursor window 100KB,
// csr write window ~3.2MB -> both L2-resident, so 4B stores coalesce in L2
// before write-back (kills the 16x write amplification seen in round 1).
__global__ __launch_bounds__(256) void k_scatter_pass(const int4* __restrict__ src4,
                                                      const int4* __restrict__ dst4,
                                                      int* __restrict__ cursor,
                                                      int* __restrict__ csr,
                                                      int lo, int hi){
  int t = blockIdx.x*256 + threadIdx.x;    // t < NE/4
  int4 d = dst4[t];
  bool bx = (d.x>=lo && d.x<hi);
  bool by = (d.y>=lo && d.y<hi);
  bool bz = (d.z>=lo && d.z<hi);
  bool bw = (d.w>=lo && d.w<hi);
  if(bx|by|bz|bw){
    int4 s = src4[t];
    if(bx){ int p = atomicAdd(&cursor[d.x], 1); csr[p] = s.x; }
    if(by){ int p = atomicAdd(&cursor[d.y], 1); csr[p] = s.y; }
    if(bz){ int p = atomicAdd(&cursor[d.z], 1); csr[p] = s.z; }
    if(bw){ int p = atomicAdd(&cursor[d.w], 1); csr[p] = s.w; }
  }
}

// ---------- h1s[row][c] = dinv[row] * (x @ W1)[row][c], 16 cols ----------
__global__ __launch_bounds__(256) void k_xw1(const float* __restrict__ x,
                                             const float* __restrict__ W1,
                                             const float* __restrict__ dinv,
                                             float* __restrict__ h1s){
  int row = blockIdx.x*256 + threadIdx.x;
  if(row >= NN) return;
  const float4* xr = (const float4*)(x + (size_t)row*FIN);  // 400B rows, 16B aligned
  float acc[16];
  #pragma unroll
  for(int c=0;c<16;c++) acc[c] = 0.f;
  #pragma unroll 5
  for(int kk=0;kk<25;kk++){
    float4 xv = xr[kk];
    const float* w = W1 + kk*4*16;   // uniform addresses -> scalar loads
    #pragma unroll
    for(int c=0;c<16;c++){
      acc[c] += xv.x*w[c] + xv.y*w[16+c] + xv.z*w[32+c] + xv.w*w[48+c];
    }
  }
  float dv = dinv[row];
  float4* o = (float4*)(h1s + (size_t)row*16);
  o[0] = make_float4(acc[0]*dv,  acc[1]*dv,  acc[2]*dv,  acc[3]*dv);
  o[1] = make_float4(acc[4]*dv,  acc[5]*dv,  acc[6]*dv,  acc[7]*dv);
  o[2] = make_float4(acc[8]*dv,  acc[9]*dv,  acc[10]*dv, acc[11]*dv);
  o[3] = make_float4(acc[12]*dv, acc[13]*dv, acc[14]*dv, acc[15]*dv);
}

// ---------- layer-1 aggregation + bias + relu + @W2, fold dinv[d] into h2s ----------
// 16 lanes per node (lane = feature), 16 nodes per 256-thread block.
__global__ __launch_bounds__(256) void k_agg1(const int* __restrict__ offs,
                                              const int* __restrict__ csr,
                                              const float* __restrict__ dinv,
                                              const float* __restrict__ h1s,
                                              const float* __restrict__ b1,
                                              const float* __restrict__ W2,
                                              float* __restrict__ h2s){
  int g = threadIdx.x >> 4;
  int f = threadIdx.x & 15;
  int d = blockIdx.x*16 + g;
  if(d >= NN) return;
  int begin = offs[d], end = offs[d+1];
  float dvd = dinv[d];
  float acc = h1s[d*16 + f];            // self loop (dinv[d] folded in h1s)
  for(int base=begin; base<end; base+=16){
    int i = base + f;
    int sE = (i < end) ? csr[i] : 0;    // coalesced 64B per group
    int cnt = end - base; if(cnt > 16) cnt = 16;
    for(int j=0;j<cnt;j++){
      int sj = __shfl(sE, j, 16);
      acc += h1s[sj*16 + f];            // 16 lanes -> one 64B line
    }
  }
  float out1 = dvd*acc + b1[f];         // segment_sum(norm*h1) + b1
  float r = fmaxf(out1, 0.f);
  float p0 = r * W2[f*2+0];
  float p1 = r * W2[f*2+1];
  #pragma unroll
  for(int o=8;o>0;o>>=1){
    p0 += __shfl_xor(p0, o, 16);
    p1 += __shfl_xor(p1, o, 16);
  }
  if(f == 0){
    h2s[d*2+0] = dvd * p0;              // pre-fold dinv[d] for layer-2 gathers
    h2s[d*2+1] = dvd * p1;
  }
}

// ---------- layer-2 aggregation for sampled nodes only + log_softmax ----------
// one wave per sampled node
__global__ __launch_bounds__(256) void k_agg2(const int* __restrict__ offs,
                                              const int* __restrict__ csr,
                                              const float* __restrict__ dinv,
                                              const float* __restrict__ h2s,
                                              const float* __restrict__ b2,
                                              float* __restrict__ gout){
  int wid = threadIdx.x >> 6;
  int l   = threadIdx.x & 63;
  int idx = blockIdx.x*4 + wid;
  if(idx >= MR) return;
  int d = idx*20;
  int begin = offs[d], end = offs[d+1];
  float dvd = dinv[d];
  float a0 = 0.f, a1 = 0.f;
  for(int i=begin+l; i<end; i+=64){
    int s = csr[i];
    a0 += h2s[s*2+0];
    a1 += h2s[s*2+1];
  }
  if(l == 0){ a0 += h2s[d*2+0]; a1 += h2s[d*2+1]; }  // self loop
  #pragma unroll
  for(int o=32;o>0;o>>=1){
    a0 += __shfl_xor(a0, o, 64);
    a1 += __shfl_xor(a1, o, 64);
  }
  if(l == 0){
    float o0 = dvd*a0 + b2[0];
    float o1 = dvd*a1 + b2[1];
    float m = fmaxf(o0, o1);
    float lse = m + logf(expf(o0-m) + expf(o1-m));
    gout[idx*2+0] = o0 - lse;
    gout[idx*2+1] = o1 - lse;
  }
}

// ---------- global min/max over BP_input ([MR,5] = 3 inputs + gout) ----------
__global__ void k_minmax(const float* __restrict__ t1, const float* __restrict__ t2,
                         const float* __restrict__ t3, const float* __restrict__ g,
                         unsigned* mm){
  int tid = blockIdx.x*blockDim.x + threadIdx.x;
  float lo = 3.4e38f, hi = -3.4e38f;
  for(int i=tid; i<5*MR; i += blockDim.x*gridDim.x){
    float v;
    if(i < MR)        v = t1[i];
    else if(i < 2*MR) v = t2[i-MR];
    else if(i < 3*MR) v = t3[i-2*MR];
    else              v = g[i-3*MR];
    lo = fminf(lo, v); hi = fmaxf(hi, v);
  }
  #pragma unroll
  for(int o=32;o>0;o>>=1){
    lo = fminf(lo, __shfl_xor(lo, o, 64));
    hi = fmaxf(hi, __shfl_xor(hi, o, 64));
  }
  __shared__ float slo[4], shi[4];
  int w = threadIdx.x >> 6, l = threadIdx.x & 63;
  if(l == 0){ slo[w] = lo; shi[w] = hi; }
  __syncthreads();
  if(threadIdx.x == 0){
    for(int j=1;j<4;j++){ lo = fminf(lo, slo[j]); hi = fmaxf(hi, shi[j]); }
    atomicMin(&mm[0], enc_f(lo));
    atomicMax(&mm[1], enc_f(hi));
  }
}

// ---------- MLP head: normalize -> 5->80 relu -> 80->10 relu -> 10->1 sigmoid ----------
__global__ __launch_bounds__(256) void k_mlp(const float* __restrict__ t1, const float* __restrict__ t2,
                                             const float* __restrict__ t3, const float* __restrict__ g,
                                             const unsigned* __restrict__ mm,
                                             const float* __restrict__ W1, const float* __restrict__ b1,
                                             const float* __restrict__ W2, const float* __restrict__ b2,
                                             const float* __restrict__ W3, const float* __restrict__ b3,
                                             float* __restrict__ out){
  int i = blockIdx.x*256 + threadIdx.x;
  if(i >= MR) return;
  float mn = dec_f(mm[0]), mx = dec_f(mm[1]);
  float sc = 1.f/(mx - mn);
  float in[5];
  in[0] = (t1[i]   - mn)*sc;
  in[1] = (t2[i]   - mn)*sc;
  in[2] = (t3[i]   - mn)*sc;
  in[3] = (g[2*i]  - mn)*sc;
  in[4] = (g[2*i+1]- mn)*sc;
  float a[80];
  #pragma unroll
  for(int j=0;j<80;j++){
    float s = b1[j];
    #pragma unroll
    for(int k=0;k<5;k++) s += in[k]*W1[k*80+j];
    a[j] = fmaxf(s, 0.f);
  }
  float h[10];
  #pragma unroll
  for(int j=0;j<10;j++){
    float s = b2[j];
    #pragma unroll
    for(int k=0;k<80;k++) s += a[k]*W2[k*10+j];
    h[j] = fmaxf(s, 0.f);
  }
  float o = b3[0];
  #pragma unroll
  for(int k=0;k<10;k++) o += h[k]*W3[k];
  out[i] = 1.f/(1.f + expf(-o));
}

extern "C" void kernel_launch(void* const* d_in, const int* in_sizes, int n_in,
                              void* d_out, int out_size, void* d_ws, size_t ws_size,
                              hipStream_t stream) {
  (void)in_sizes; (void)n_in; (void)out_size; (void)ws_size;
  const int*   eidx    = (const int*)  d_in[0];   // [2, NE]
  const int4*  src4    = (const int4*) eidx;
  const int4*  dst4    = (const int4*)(eidx + NE);
  const float* x       = (const float*)d_in[1];   // [NN, 100]
  const float* transE  = (const float*)d_in[4];
  const float* ComplEx = (const float*)d_in[5];
  const float* path    = (const float*)d_in[6];
  const float* ghW1    = (const float*)d_in[8];
  const float* ghb1    = (const float*)d_in[9];
  const float* ghW2    = (const float*)d_in[10];
  const float* ghb2    = (const float*)d_in[11];
  const float* mW1     = (const float*)d_in[16];
  const float* mb1     = (const float*)d_in[17];
  const float* mW2     = (const float*)d_in[18];
  const float* mb2     = (const float*)d_in[19];
  const float* mW3     = (const float*)d_in[20];
  const float* mb3     = (const float*)d_in[21];
  float* out = (float*)d_out;

  // workspace carve-up (~44 MB)
  char* w = (char*)d_ws;
  size_t off = 0;
  auto alloc = [&](size_t bytes)->void*{
    void* p = w + off;
    off += (bytes + 255) & ~(size_t)255;
    return p;
  };
  int*      deg    = (int*)     alloc((size_t)NN*4);
  int*      offs   = (int*)     alloc((size_t)(NN+1)*4);
  int*      cursor = (int*)     alloc((size_t)NN*4);
  int*      csr    = (int*)     alloc((size_t)NE*4);
  float*    dinv   = (float*)   alloc((size_t)NN*4);
  float*    h1s    = (float*)   alloc((size_t)NN*16*4);
  float*    h2s    = (float*)   alloc((size_t)NN*2*4);
  float*    gout   = (float*)   alloc((size_t)MR*2*4);
  unsigned* mm     = (unsigned*)alloc(256);
  int*      part   = (int*)     alloc(256*4);

  const int EB4 = (NE/4 + 255)/256;   // edge blocks for int4 kernels (6250)

  k_init     <<<(NN+255)/256, 256, 0, stream>>>(deg, offs, mm);
  for(int p=0;p<NPASS;p++)
    k_deg_pass <<<EB4, 256, 0, stream>>>(dst4, deg, p*PRANGE, (p+1)*PRANGE);
  k_dinv     <<<(NN+255)/256, 256, 0, stream>>>(deg, dinv);
  k_scan_part<<<SCAN_NB, 256, 0, stream>>>(deg, part);
  k_scan_top <<<1, 256, 0, stream>>>(part, SCAN_NB);
  k_scan_fin <<<SCAN_NB, 256, 0, stream>>>(deg, part, offs, cursor);
  for(int p=0;p<NPASS;p++)
    k_scatter_pass<<<EB4, 256, 0, stream>>>(src4, dst4, cursor, csr,
                                            p*PRANGE, (p+1)*PRANGE);
  k_xw1      <<<(NN+255)/256, 256, 0, stream>>>(x, ghW1, dinv, h1s);
  k_agg1     <<<NN/16, 256, 0, stream>>>(offs, csr, dinv, h1s, ghb1, ghW2, h2s);
  k_agg2     <<<(MR+3)/4, 256, 0, stream>>>(offs, csr, dinv, h2s, ghb2, gout);
  k_minmax   <<<32, 256, 0, stream>>>(transE, ComplEx, path, gout, mm);
  k_mlp      <<<(MR+255)/256, 256, 0, stream>>>(transE, ComplEx, path, gout, mm,
                                                mW1, mb1, mW2, mb2, mW3, mb3, out);
}